// Round 1
// baseline (464.912 us; speedup 1.0000x reference)
//
#include <hip/hip_runtime.h>
#include <stdint.h>

#define T_LEN 512
#define VOCAB 101
// G table: f32, layout [v][unit][gate], unit split as (q = u>>3)*QW + (jt = u&7)*4
// pitches chosen for bank spread on ds_read_b128: GPW%32=20 (v spread), QW%32=4 (q spread)
#define GPW   148   // G row pitch in f32 words (592 B)
#define QW    36    // q-block pitch in f32 words (144 B)

typedef short short8 __attribute__((ext_vector_type(8)));
typedef float f32x4  __attribute__((ext_vector_type(4)));

#define LOG2E 1.442695041f
#define L2E2  2.885390082f   // 2*log2(e)

__device__ __forceinline__ float bf2f(uint16_t u) {
    union { uint32_t i; float f; } x; x.i = ((uint32_t)u) << 16; return x.f;
}
__device__ __forceinline__ uint16_t f2bf(float f) {
    union { float f; uint32_t i; } x; x.f = f;
    return (uint16_t)((x.i + 0x7FFFu + ((x.i >> 16) & 1u)) >> 16);
}
__device__ __forceinline__ float getw(const void* p, int i, bool isbf) {
    return isbf ? bf2f(((const uint16_t*)p)[i]) : ((const float*)p)[i];
}
__device__ __forceinline__ bool detect_bf16(const void* embp) {
    const uint16_t* u = (const uint16_t*)embp;
    int sane = 0;
    for (int i = 0; i < 64; ++i) {
        uint16_t v = u[i];
        int e = (v >> 7) & 0xFF;
        sane += ((e >= 100 && e <= 140) || ((v & 0x7FFFu) == 0)) ? 1 : 0;
    }
    return sane >= 56;
}

// One timestep, fully in registers.
//   GC: G fragments (f32x4 x8) for THIS step (= MFMA C operand, pre-scaled preact bias)
//   GN: register buffer to prefetch G for NEXT step
//   VN: token for next step
// D-layout per lane (n,q): s_[jt][reg] = preact(gate=reg, unit=8q+jt, row=n)
// (i,f gates & o pre-scaled by log2e; g gate pre-scaled by 2log2e; c kept in 2log2e scale)
#define STEP(GC, GN, VN)                                                              \
  {                                                                                   \
    const f32x4* gp_ = (const f32x4*)&Gl[(VN) * GPW + q * QW];                        \
    _Pragma("unroll")                                                                 \
    for (int jt = 0; jt < 8; ++jt) GN[jt] = gp_[jt];                                  \
    f32x4 s_[8];                                                                      \
    _Pragma("unroll")                                                                 \
    for (int jt = 0; jt < 8; ++jt)                                                    \
      s_[jt] = __builtin_amdgcn_mfma_f32_16x16x32_bf16(afr[jt], bfr, GC[jt], 0, 0, 0);\
    _Pragma("unroll")                                                                 \
    for (int jt = 0; jt < 8; ++jt) {                                                  \
      float ai = __builtin_amdgcn_exp2f(-s_[jt][0]);   /* e^-i  */                    \
      float af = __builtin_amdgcn_exp2f(-s_[jt][1]);   /* e^-f  */                    \
      float ag = __builtin_amdgcn_exp2f(-s_[jt][2]);   /* e^-2g */                    \
      float ao = __builtin_amdgcn_exp2f(-s_[jt][3]);   /* e^-o  */                    \
      float uu = 1.f + ai, ww = 1.f + ag, zz = 1.f + af;                              \
      float uw = uu * ww;                                                             \
      /* c' (2log2e-scaled) = [c*uu*ww + 2log2e*(1-ag)*zz] / (zz*uu*ww) */            \
      float num = __builtin_fmaf(__builtin_fmaf(ww, -L2E2, 2.f * L2E2), zz,           \
                                 cst[jt] * uw);                                       \
      float cs = num * __builtin_amdgcn_rcpf(zz * uw);                                \
      cst[jt] = cs;                                                                   \
      float ac = __builtin_amdgcn_exp2f(-cs);          /* e^-2c */                    \
      float t1 = 1.f + ac;                                                            \
      /* h = sigm(o)*tanh(c) = (1-ac) / ((1+ao)*(1+ac)) */                            \
      hv[jt] = (2.f - t1) * __builtin_amdgcn_rcpf((1.f + ao) * t1);                   \
    }                                                                                 \
    union { short8 v; uint32_t w4[4]; } ub_;                                          \
    _Pragma("unroll")                                                                 \
    for (int p = 0; p < 4; ++p)                                                       \
      asm("v_cvt_pk_bf16_f32 %0, %1, %2"                                              \
          : "=v"(ub_.w4[p]) : "v"(hv[2 * p]), "v"(hv[2 * p + 1]));                    \
    bfr = ub_.v;                                                                      \
  }

__global__ __launch_bounds__(128, 1) void lstm_fused(
    const int* __restrict__ x, const void* __restrict__ emb,
    const void* __restrict__ Wx, const void* __restrict__ Wh,
    const void* __restrict__ bias, const void* __restrict__ Wfc,
    const void* __restrict__ bfc, void* __restrict__ out)
{
    __shared__ __align__(16) float Gl[VOCAB * GPW];   // 59,792 B, read-only after init

    const int tid = threadIdx.x;
    const int wl  = tid & 63;
    const int w   = tid >> 6;       // wave 0..1: independent 16-row group each
    const int n   = wl & 15;        // batch row within group (MFMA B-col / A-m)
    const int q   = wl >> 4;        // k-quad; lane owns units 8q..8q+7
    const int row = blockIdx.x * 32 + 16 * w + n;

    const bool isbf = detect_bf16(emb);

    // ---- build G[v][u][g] = scale(g) * (emb[v]@Wx + b)[32g+u], f32 in LDS ----
    // scale: g-gate gets 2log2e (so exp2 arg is -2g' directly), others log2e
    for (int idx = tid; idx < VOCAB * 128; idx += 128) {
        int v = idx >> 7, col = idx & 127;
        int g = col >> 5, u = col & 31;
        float acc = getw(bias, col, isbf);
        #pragma unroll 8
        for (int k = 0; k < 32; ++k)
            acc += getw(emb, v * 32 + k, isbf) * getw(Wx, k * 128 + col, isbf);
        float sc = (g == 2) ? L2E2 : LOG2E;
        Gl[v * GPW + (u >> 3) * QW + (u & 7) * 4 + g] = acc * sc;
    }

    // ---- A fragments: tile jt covers units {jt, 8+jt, 16+jt, 24+jt} so that
    //      D-row r=4q+reg of tile jt = gate reg of unit 8q+jt (h stays lane-local).
    //      A[m=n][k=8q+jj] = scale(n&3) * Wh[8q+jj][32*(n&3) + 8*(n>>2) + jt] ----
    short8 afr[8];
    {
        const int gte = n & 3, ul = n >> 2;
        const float sc = (gte == 2) ? L2E2 : LOG2E;
        #pragma unroll
        for (int jt = 0; jt < 8; ++jt) {
            union { short8 v; uint16_t s[8]; } ua;
            #pragma unroll
            for (int jj = 0; jj < 8; ++jj)
                ua.s[jj] = f2bf(getw(Wh, (8 * q + jj) * 128 + 32 * gte + 8 * ul + jt,
                                     isbf) * sc);
            afr[jt] = ua.v;
        }
    }
    __syncthreads();   // the ONLY barrier: Gl ready. No sync in the time loop.

    // ---- register-resident recurrence state ----
    float  cst[8] = {0, 0, 0, 0, 0, 0, 0, 0};   // cell state (2log2e scale), unit 8q+jt
    float  hv[8];                               // last h values (f32)
    short8 bfr = {0, 0, 0, 0, 0, 0, 0, 0};      // B fragment: h[n][8q..8q+7], bf16
    f32x4  gA[8], gB[8];                        // double-buffered G fragments

    const int* xrow = x + row * T_LEN;
    int4 tokv = *(const int4*)xrow;             // tokens t=0..3
    {
        const f32x4* gp = (const f32x4*)&Gl[tokv.x * GPW + q * QW];
        #pragma unroll
        for (int jt = 0; jt < 8; ++jt) gA[jt] = gp[jt];
    }

    for (int tb = 0; tb < T_LEN / 4; ++tb) {
        // tokens for t in [4tb+4, 4tb+7], issued ~2800 cycles before first use
        int4 tokn = *(const int4*)&xrow[(4 * tb + 4) & (T_LEN - 1)];
        STEP(gA, gB, tokv.y);
        STEP(gB, gA, tokv.z);
        STEP(gA, gB, tokv.w);
        STEP(gB, gA, tokn.x);
        tokv = tokn;
    }

    // ---- epilogue: out = h(T-1) @ W_fc + b_fc ; h lives in hv[] ----
    float p0 = 0.f, p1 = 0.f;
    #pragma unroll
    for (int jt = 0; jt < 8; ++jt) {
        p0 = __builtin_fmaf(hv[jt], getw(Wfc, (8 * q + jt) * 2 + 0, isbf), p0);
        p1 = __builtin_fmaf(hv[jt], getw(Wfc, (8 * q + jt) * 2 + 1, isbf), p1);
    }
    p0 += __shfl_xor(p0, 16);  p0 += __shfl_xor(p0, 32);
    p1 += __shfl_xor(p1, 16);  p1 += __shfl_xor(p1, 32);
    if (q == 0) {
        float o0 = p0 + getw(bfc, 0, isbf);
        float o1 = p1 + getw(bfc, 1, isbf);
        if (isbf) {
            ((uint16_t*)out)[row * 2 + 0] = f2bf(o0);
            ((uint16_t*)out)[row * 2 + 1] = f2bf(o1);
        } else {
            ((float*)out)[row * 2 + 0] = o0;
            ((float*)out)[row * 2 + 1] = o1;
        }
    }
}

extern "C" void kernel_launch(void* const* d_in, const int* in_sizes, int n_in,
                              void* d_out, int out_size, void* d_ws, size_t ws_size,
                              hipStream_t stream) {
    (void)in_sizes; (void)n_in; (void)d_ws; (void)ws_size; (void)out_size;
    const int* x = (const int*)d_in[0];
    lstm_fused<<<dim3(128), dim3(128), 0, stream>>>(
        x, d_in[1], d_in[2], d_in[3], d_in[4], d_in[5], d_in[6], d_out);
}

// Round 2
// 283.799 us; speedup vs baseline: 1.6382x; 1.6382x over previous
//
#include <hip/hip_runtime.h>
#include <stdint.h>

#define T_LEN 512
#define VOCAB 101
#define GP    132   // G row pitch in f32 words: [u<32][g<4] data + 4 pad (GP%32=4 -> v spread)
#define XPB   516   // token row pitch bytes (129 dwords, odd -> bank spread)
#define HPW   20    // h row pitch in dwords (16 data + 4 pad; 20%32 spreads rows 2-way)

typedef short short8 __attribute__((ext_vector_type(8)));
typedef float f32x4  __attribute__((ext_vector_type(4)));

#define LOG2E 1.442695041f
#define L2E2  2.885390082f   // 2*log2(e)

__device__ __forceinline__ float asF(uint32_t u) {
    union { uint32_t i; float f; } x; x.i = u; return x.f;
}
__device__ __forceinline__ float bf2f(uint16_t u) { return asF(((uint32_t)u) << 16); }
__device__ __forceinline__ float bf_lo(uint32_t u) { return asF(u << 16); }
__device__ __forceinline__ float bf_hi(uint32_t u) { return asF(u & 0xFFFF0000u); }
__device__ __forceinline__ uint16_t f2bf(float f) {
    union { float f; uint32_t i; } x; x.f = f;
    return (uint16_t)((x.i + 0x7FFFu + ((x.i >> 16) & 1u)) >> 16);
}
__device__ __forceinline__ float getw(const void* p, int i, bool isbf) {
    return isbf ? bf2f(((const uint16_t*)p)[i]) : ((const float*)p)[i];
}
__device__ __forceinline__ bool detect_bf16(const void* embp) {
    const uint16_t* u = (const uint16_t*)embp;
    int sane = 0;
    for (int i = 0; i < 64; ++i) {
        uint16_t v = u[i];
        int e = (v >> 7) & 0xFF;
        sane += ((e >= 100 && e <= 140) || ((v & 0x7FFFu) == 0)) ? 1 : 0;
    }
    return sane >= 56;
}

// gates for one unit: S = f32x4 preacts (i,f,g,o; i/f/o log2e-scaled, g 2log2e-scaled),
// CST = cell state (2log2e scale). Emits h (f32). 5 exp2 + 2 rcp. Verified in r1.
#define GATES(S, CST, HOUT)                                                     \
  {                                                                             \
    float ai = __builtin_amdgcn_exp2f(-(S)[0]);                                 \
    float af = __builtin_amdgcn_exp2f(-(S)[1]);                                 \
    float ag = __builtin_amdgcn_exp2f(-(S)[2]);                                 \
    float ao = __builtin_amdgcn_exp2f(-(S)[3]);                                 \
    float uu = 1.f + ai, ww = 1.f + ag, zz = 1.f + af;                          \
    float uw = uu * ww;                                                         \
    float num = __builtin_fmaf(__builtin_fmaf(ww, -L2E2, 2.f * L2E2), zz,       \
                               (CST) * uw);                                     \
    float cs = num * __builtin_amdgcn_rcpf(zz * uw);                            \
    (CST) = cs;                                                                 \
    float ac = __builtin_amdgcn_exp2f(-cs);                                     \
    float t1 = 1.f + ac;                                                        \
    (HOUT) = (2.f - t1) * __builtin_amdgcn_rcpf((1.f + ao) * t1);               \
  }

__global__ __launch_bounds__(256, 1) void lstm_fused(
    const int* __restrict__ x, const void* __restrict__ emb,
    const void* __restrict__ Wx, const void* __restrict__ Wh,
    const void* __restrict__ bias, const void* __restrict__ Wfc,
    const void* __restrict__ bfc, void* __restrict__ out)
{
    __shared__ __align__(16) float    Gl[VOCAB * GP];       // 53,328 B, f32 preact bias
    __shared__ __align__(16) uint8_t  xt8[16 * XPB];        //  8,256 B packed tokens
    __shared__ __align__(16) uint32_t hbuf[2 * 16 * HPW];   //  2,560 B dbl-buffered h

    const int tid = threadIdx.x;
    const int wl  = tid & 63;
    const int w   = tid >> 6;       // wave 0..3: owns units 8w..8w+7
    const int n   = wl & 15;        // batch row within group
    const int q   = wl >> 4;        // lane owns units 8w+2q, 8w+2q+1
    const int b0  = blockIdx.x * 16;

    const bool isbf = detect_bf16(emb);

    // ---- build G[v][u][g] = scale(g) * (emb[v]@Wx + b)[32g+u], f32 ----
    for (int idx = tid; idx < VOCAB * 128; idx += 256) {
        int v = idx >> 7, cc = idx & 127;
        int u = cc >> 2, g = cc & 3;
        int col = 32 * g + u;
        float acc = getw(bias, col, isbf);
        #pragma unroll 8
        for (int k = 0; k < 32; ++k)
            acc += getw(emb, v * 32 + k, isbf) * getw(Wx, k * 128 + col, isbf);
        Gl[v * GP + cc] = acc * ((g == 2) ? L2E2 : LOG2E);
    }
    // ---- pack x tokens to u8 for all 512 steps ----
    for (int i = tid; i < 2048; i += 256) {
        int row = i >> 7, c4 = i & 127;
        int4 vv = *(const int4*)&x[(b0 + row) * T_LEN + (c4 << 2)];
        uint32_t p = (uint32_t)(vv.x & 255) | ((uint32_t)(vv.y & 255) << 8) |
                     ((uint32_t)(vv.z & 255) << 16) | ((uint32_t)(vv.w & 255) << 24);
        ((uint32_t*)&xt8[row * XPB])[c4] = p;
    }
    // ---- zero h buffers ----
    for (int i = tid; i < 2 * 16 * HPW; i += 256) hbuf[i] = 0;

    // ---- A fragments: tile jt in {0,1}; D-row m of tile jt <-> (gate m&3,
    //      unit 8w + 2*(m>>2) + jt). A[m=n][k=8q+jj] = sc(n&3)*Wh[8q+jj][col] ----
    short8 afr0, afr1;
    {
        const int gte = n & 3, ul = n >> 2;
        const float sc = (gte == 2) ? L2E2 : LOG2E;
        const int base = 32 * gte + 8 * w + 2 * ul;
        union { short8 v; uint16_t s[8]; } u0, u1;
        #pragma unroll
        for (int jj = 0; jj < 8; ++jj) {
            int kk = 8 * q + jj;
            u0.s[jj] = f2bf(getw(Wh, kk * 128 + base,     isbf) * sc);
            u1.s[jj] = f2bf(getw(Wh, kk * 128 + base + 1, isbf) * sc);
        }
        afr0 = u0.v; afr1 = u1.v;
    }
    __syncthreads();

    const int u0i = 8 * w + 2 * q;      // lane's even unit (tile 0)
    float c0 = 0.f, c1 = 0.f;
    const uint8_t* xr = &xt8[n * XPB];

    // prefetch: C fragments for t=0, token for t=1
    f32x4 gc0, gc1;
    {
        const f32x4* gp = (const f32x4*)&Gl[(int)xr[0] * GP + u0i * 4];
        gc0 = gp[0]; gc1 = gp[1];
    }
    int tokA = xr[1];

    for (int t = 0; t < T_LEN; ++t) {
        const uint32_t* hr = &hbuf[(t & 1) * (16 * HPW)];
        uint32_t*       hw = &hbuf[((t & 1) ^ 1) * (16 * HPW)];
        // B fragment: h(t-1)[n][8q..8q+7] (issued first -> MFMA waits only on this)
        short8 bfrag = *(const short8*)&hr[n * HPW + 4 * q];
        f32x4 s0 = __builtin_amdgcn_mfma_f32_16x16x32_bf16(afr0, bfrag, gc0, 0, 0, 0);
        f32x4 s1 = __builtin_amdgcn_mfma_f32_16x16x32_bf16(afr1, bfrag, gc1, 0, 0, 0);
        // prefetch C fragments for t+1 (token already in reg) and token for t+2
        f32x4 gn0, gn1;
        {
            const f32x4* gp = (const f32x4*)&Gl[tokA * GP + u0i * 4];
            gn0 = gp[0]; gn1 = gp[1];
        }
        int tokN = xr[(t + 2) & (T_LEN - 1)];
        // gates for the lane's two adjacent units
        float h0, h1;
        GATES(s0, c0, h0);
        GATES(s1, c1, h1);
        uint32_t hp;
        asm("v_cvt_pk_bf16_f32 %0, %1, %2" : "=v"(hp) : "v"(h0), "v"(h1));
        hw[n * HPW + 4 * w + q] = hp;
        gc0 = gn0; gc1 = gn1; tokA = tokN;
        __syncthreads();   // no VMEM in flight -> lgkm-only drain
    }

    // ---- epilogue: out = h(T-1) @ W_fc + b_fc ; h(511) lives in buf 0 ----
    if (tid < 32) {
        int row = tid >> 1, cc = tid & 1;
        float acc = getw(bfc, cc, isbf);
        #pragma unroll 8
        for (int k = 0; k < 32; ++k) {
            uint32_t d = hbuf[row * HPW + (k >> 1)];
            float hval = (k & 1) ? bf_hi(d) : bf_lo(d);
            acc += hval * getw(Wfc, k * 2 + cc, isbf);
        }
        int oidx = (b0 + row) * 2 + cc;
        if (isbf) ((uint16_t*)out)[oidx] = f2bf(acc);
        else      ((float*)out)[oidx]    = acc;
    }
}

extern "C" void kernel_launch(void* const* d_in, const int* in_sizes, int n_in,
                              void* d_out, int out_size, void* d_ws, size_t ws_size,
                              hipStream_t stream) {
    (void)in_sizes; (void)n_in; (void)d_ws; (void)ws_size; (void)out_size;
    const int* x = (const int*)d_in[0];
    lstm_fused<<<dim3(256), dim3(256), 0, stream>>>(
        x, d_in[1], d_in[2], d_in[3], d_in[4], d_in[5], d_in[6], d_out);
}

// Round 3
// 283.442 us; speedup vs baseline: 1.6402x; 1.0013x over previous
//
#include <hip/hip_runtime.h>
#include <stdint.h>

#define T_LEN 512
#define VOCAB 101
#define GP    132   // G row pitch in f32 words: [u<32][g<4] data + 4 pad (GP%32=4 -> v spread)
#define XPB   516   // token row pitch bytes (129 dwords, odd -> bank spread)
#define HPW   20    // h row pitch in dwords (16 data + 4 pad; 2-way max alias on b128 = free)
#define HB1   (16 * HPW)

typedef short short8 __attribute__((ext_vector_type(8)));
typedef float f32x4  __attribute__((ext_vector_type(4)));

#define LOG2E 1.442695041f
#define L2E2  2.885390082f   // 2*log2(e)

__device__ __forceinline__ float asF(uint32_t u) {
    union { uint32_t i; float f; } x; x.i = u; return x.f;
}
__device__ __forceinline__ float bf2f(uint16_t u) { return asF(((uint32_t)u) << 16); }
__device__ __forceinline__ float bf_lo(uint32_t u) { return asF(u << 16); }
__device__ __forceinline__ float bf_hi(uint32_t u) { return asF(u & 0xFFFF0000u); }
__device__ __forceinline__ uint16_t f2bf(float f) {
    union { float f; uint32_t i; } x; x.f = f;
    return (uint16_t)((x.i + 0x7FFFu + ((x.i >> 16) & 1u)) >> 16);
}
__device__ __forceinline__ float getw(const void* p, int i, bool isbf) {
    return isbf ? bf2f(((const uint16_t*)p)[i]) : ((const float*)p)[i];
}
__device__ __forceinline__ bool detect_bf16(const void* embp) {
    const uint16_t* u = (const uint16_t*)embp;
    int sane = 0;
    for (int i = 0; i < 64; ++i) {
        uint16_t v = u[i];
        int e = (v >> 7) & 0xFF;
        sane += ((e >= 100 && e <= 140) || ((v & 0x7FFFu) == 0)) ? 1 : 0;
    }
    return sane >= 56;
}

// gates for one unit: S = f32x4 preacts (i,f,g,o; i/f/o log2e-scaled, g 2log2e-scaled),
// CST = cell state (2log2e scale). Emits h (f32). 5 exp2 + 2 rcp. Verified r1/r2.
#define GATES(S, CST, HOUT)                                                     \
  {                                                                             \
    float ai = __builtin_amdgcn_exp2f(-(S)[0]);                                 \
    float af = __builtin_amdgcn_exp2f(-(S)[1]);                                 \
    float ag = __builtin_amdgcn_exp2f(-(S)[2]);                                 \
    float ao = __builtin_amdgcn_exp2f(-(S)[3]);                                 \
    float uu = 1.f + ai, ww = 1.f + ag, zz = 1.f + af;                          \
    float uw = uu * ww;                                                         \
    float num = __builtin_fmaf(__builtin_fmaf(ww, -L2E2, 2.f * L2E2), zz,       \
                               (CST) * uw);                                     \
    float cs = num * __builtin_amdgcn_rcpf(zz * uw);                            \
    (CST) = cs;                                                                 \
    float ac = __builtin_amdgcn_exp2f(-cs);                                     \
    float t1 = 1.f + ac;                                                        \
    (HOUT) = (2.f - t1) * __builtin_amdgcn_rcpf((1.f + ao) * t1);               \
  }

// One timestep. Tail order is PINNED: h-write < {G-prefetch, tok-read} <
// s_waitcnt lgkmcnt(3) < s_barrier. At the waitcnt exactly 4 lgkm ops are
// outstanding (write,G0,G1,tok) -- the compiler must have drained to 0 before
// the MFMA (bfrag is the newest ds_read), so the count is deterministic.
// lgkmcnt(3) retires the oldest = the h-write -> visible at barrier. The G/tok
// reads (read-only LDS) stay in flight across the barrier and complete under
// the next step's [barrier + h-read + MFMA] window instead of on the chain.
#define STEP_T(HRoff, HWoff)                                                      \
  {                                                                               \
    const uint32_t* hr = &hbuf[HRoff];                                            \
    uint32_t*       hw = &hbuf[HWoff];                                            \
    short8 bfrag = *(const short8*)&hr[n * HPW + 4 * q];                          \
    f32x4 s0 = __builtin_amdgcn_mfma_f32_16x16x32_bf16(afr0, bfrag, gc0, 0, 0, 0);\
    f32x4 s1 = __builtin_amdgcn_mfma_f32_16x16x32_bf16(afr1, bfrag, gc1, 0, 0, 0);\
    float h0, h1;                                                                 \
    GATES(s0, c0, h0);                                                            \
    GATES(s1, c1, h1);                                                            \
    uint32_t hp;                                                                  \
    asm("v_cvt_pk_bf16_f32 %0, %1, %2" : "=v"(hp) : "v"(h0), "v"(h1));            \
    hw[n * HPW + 4 * w + q] = hp;                                                 \
    __builtin_amdgcn_sched_barrier(0);                                            \
    {                                                                             \
      const f32x4* gp = (const f32x4*)&Gl[tokA * GP + u0i * 4];                   \
      gc0 = gp[0]; gc1 = gp[1];                                                   \
    }                                                                             \
    tokA = xr[tnext & (T_LEN - 1)];                                               \
    ++tnext;                                                                      \
    __builtin_amdgcn_sched_barrier(0);                                            \
    asm volatile("s_waitcnt lgkmcnt(3)" ::: "memory");                            \
    __builtin_amdgcn_s_barrier();                                                 \
    __builtin_amdgcn_sched_barrier(0);                                            \
  }

__global__ __launch_bounds__(256, 1) void lstm_fused(
    const int* __restrict__ x, const void* __restrict__ emb,
    const void* __restrict__ Wx, const void* __restrict__ Wh,
    const void* __restrict__ bias, const void* __restrict__ Wfc,
    const void* __restrict__ bfc, void* __restrict__ out)
{
    __shared__ __align__(16) float    Gl[VOCAB * GP];       // 53,328 B f32 preact bias
    __shared__ __align__(16) uint8_t  xt8[16 * XPB];        //  8,256 B packed tokens
    __shared__ __align__(16) uint32_t hbuf[2 * 16 * HPW];   //  2,560 B dbl-buffered h

    const int tid = threadIdx.x;
    const int wl  = tid & 63;
    const int w   = tid >> 6;       // wave 0..3: owns units 8w..8w+7
    const int n   = wl & 15;        // batch row within group
    const int q   = wl >> 4;        // lane owns units 8w+2q, 8w+2q+1
    const int b0  = blockIdx.x * 16;

    const bool isbf = detect_bf16(emb);

    // ---- build G[v][u][g] = scale(g) * (emb[v]@Wx + b)[32g+u], f32 ----
    for (int idx = tid; idx < VOCAB * 128; idx += 256) {
        int v = idx >> 7, cc = idx & 127;
        int u = cc >> 2, g = cc & 3;
        int col = 32 * g + u;
        float acc = getw(bias, col, isbf);
        #pragma unroll 8
        for (int k = 0; k < 32; ++k)
            acc += getw(emb, v * 32 + k, isbf) * getw(Wx, k * 128 + col, isbf);
        Gl[v * GP + cc] = acc * ((g == 2) ? L2E2 : LOG2E);
    }
    // ---- pack x tokens to u8 for all 512 steps ----
    for (int i = tid; i < 2048; i += 256) {
        int row = i >> 7, c4 = i & 127;
        int4 vv = *(const int4*)&x[(b0 + row) * T_LEN + (c4 << 2)];
        uint32_t p = (uint32_t)(vv.x & 255) | ((uint32_t)(vv.y & 255) << 8) |
                     ((uint32_t)(vv.z & 255) << 16) | ((uint32_t)(vv.w & 255) << 24);
        ((uint32_t*)&xt8[row * XPB])[c4] = p;
    }
    // ---- zero h buffers ----
    for (int i = tid; i < 2 * 16 * HPW; i += 256) hbuf[i] = 0;

    // ---- A fragments: tile jt in {0,1}; D-row m of tile jt <-> (gate m&3,
    //      unit 8w + 2*(m>>2) + jt). A[m=n][k=8q+jj] = sc(n&3)*Wh[8q+jj][col] ----
    short8 afr0, afr1;
    {
        const int gte = n & 3, ul = n >> 2;
        const float sc = (gte == 2) ? L2E2 : LOG2E;
        const int base = 32 * gte + 8 * w + 2 * ul;
        union { short8 v; uint16_t s[8]; } u0, u1;
        #pragma unroll
        for (int jj = 0; jj < 8; ++jj) {
            int kk = 8 * q + jj;
            u0.s[jj] = f2bf(getw(Wh, kk * 128 + base,     isbf) * sc);
            u1.s[jj] = f2bf(getw(Wh, kk * 128 + base + 1, isbf) * sc);
        }
        afr0 = u0.v; afr1 = u1.v;
    }
    __syncthreads();

    const int u0i = 8 * w + 2 * q;      // lane's even unit (tile 0)
    float c0 = 0.f, c1 = 0.f;
    const uint8_t* xr = &xt8[n * XPB];

    // prefetch: C fragments for t=0, token for t=1; tnext indexes t=2
    f32x4 gc0, gc1;
    {
        const f32x4* gp = (const f32x4*)&Gl[(int)xr[0] * GP + u0i * 4];
        gc0 = gp[0]; gc1 = gp[1];
    }
    int tokA  = xr[1];
    int tnext = 2;

    for (int t = 0; t < T_LEN; t += 2) {
        STEP_T(0,   HB1);   // even step: read buf0, write buf1
        STEP_T(HB1, 0);     // odd  step: read buf1, write buf0
    }

    __syncthreads();   // full drain before epilogue reads

    // ---- epilogue: out = h(T-1) @ W_fc + b_fc ; h(511) lives in buf 0 ----
    if (tid < 32) {
        int row = tid >> 1, cc = tid & 1;
        float acc = getw(bfc, cc, isbf);
        #pragma unroll 8
        for (int k = 0; k < 32; ++k) {
            uint32_t d = hbuf[row * HPW + (k >> 1)];
            float hval = (k & 1) ? bf_hi(d) : bf_lo(d);
            acc += hval * getw(Wfc, k * 2 + cc, isbf);
        }
        int oidx = (b0 + row) * 2 + cc;
        if (isbf) ((uint16_t*)out)[oidx] = f2bf(acc);
        else      ((float*)out)[oidx]    = acc;
    }
}

extern "C" void kernel_launch(void* const* d_in, const int* in_sizes, int n_in,
                              void* d_out, int out_size, void* d_ws, size_t ws_size,
                              hipStream_t stream) {
    (void)in_sizes; (void)n_in; (void)d_ws; (void)ws_size; (void)out_size;
    const int* x = (const int*)d_in[0];
    lstm_fused<<<dim3(256), dim3(256), 0, stream>>>(
        x, d_in[1], d_in[2], d_in[3], d_in[4], d_in[5], d_in[6], d_out);
}